// Round 1
// baseline (499.871 us; speedup 1.0000x reference)
//
#include <hip/hip_runtime.h>
#include <math.h>

#define Nn 8192
#define Cc 256
#define Dd 128
#define CAP 2048   // max edges/row; binomial(8192,0.01) max ~140, huge margin

// h[n][d] = sum_c x[n][c] * W[d][c]   (fp32, small GEMM: 0.5 GFLOP)
__global__ __launch_bounds__(256) void h_kernel(const float* __restrict__ x,
                                                const float* __restrict__ W,
                                                float* __restrict__ h) {
  __shared__ float xs[8 * Cc];  // 8 rows of inputs, 8 KB
  const int tid = threadIdx.x;
  const int row0 = blockIdx.x * 8;
  // stage 8 input rows (2048 floats = 512 float4) cooperatively
  const float4* xg = (const float4*)(x + (size_t)row0 * Cc);
  float4* xs4 = (float4*)xs;
  xs4[tid] = xg[tid];
  xs4[tid + 256] = xg[tid + 256];
  __syncthreads();
  const int d = tid & 127;
  const int half = tid >> 7;     // each half of the block does 4 rows
  const float4* w4 = (const float4*)(W + (size_t)d * Cc);
  const float4* xr0 = (const float4*)(xs + (half * 4 + 0) * Cc);
  const float4* xr1 = (const float4*)(xs + (half * 4 + 1) * Cc);
  const float4* xr2 = (const float4*)(xs + (half * 4 + 2) * Cc);
  const float4* xr3 = (const float4*)(xs + (half * 4 + 3) * Cc);
  float acc0 = 0.f, acc1 = 0.f, acc2 = 0.f, acc3 = 0.f;
#pragma unroll 8
  for (int c4 = 0; c4 < Cc / 4; ++c4) {
    const float4 w = w4[c4];
    const float4 a0 = xr0[c4];
    const float4 a1 = xr1[c4];
    const float4 a2 = xr2[c4];
    const float4 a3 = xr3[c4];
    acc0 += a0.x * w.x + a0.y * w.y + a0.z * w.z + a0.w * w.w;
    acc1 += a1.x * w.x + a1.y * w.y + a1.z * w.z + a1.w * w.w;
    acc2 += a2.x * w.x + a2.y * w.y + a2.z * w.z + a2.w * w.w;
    acc3 += a3.x * w.x + a3.y * w.y + a3.z * w.z + a3.w * w.w;
  }
  const int r0 = row0 + half * 4;
  h[(size_t)(r0 + 0) * Dd + d] = acc0;
  h[(size_t)(r0 + 1) * Dd + d] = acc1;
  h[(size_t)(r0 + 2) * Dd + d] = acc2;
  h[(size_t)(r0 + 3) * Dd + d] = acc3;
}

// One block per row i: scan graph row -> edge list -> sparse masked softmax
// -> weighted sum of h_j + bias.
__global__ __launch_bounds__(256) void gat_kernel(const float* __restrict__ graph,
                                                  const float* __restrict__ h,
                                                  const float* __restrict__ bias,
                                                  float* __restrict__ out) {
  __shared__ float hi[Dd];
  __shared__ int   idx[CAP];
  __shared__ float sc[CAP];
  __shared__ int   cnt;
  __shared__ float wred[4];
  __shared__ float accs[Dd];
  const int i = blockIdx.x;
  const int tid = threadIdx.x;
  if (tid == 0) cnt = 0;
  if (tid < Dd) hi[tid] = h[(size_t)i * Dd + tid];
  __syncthreads();

  // ---- Phase A: scan graph row (32 KB, coalesced float4), build edge list
  const float4* g4 = (const float4*)(graph + (size_t)i * Nn);
#pragma unroll
  for (int t = 0; t < (Nn / 4) / 256; ++t) {
    const int c4 = t * 256 + tid;
    const float4 g = g4[c4];
    if (g.x != 0.f) { int p = atomicAdd(&cnt, 1); if (p < CAP) idx[p] = 4 * c4 + 0; }
    if (g.y != 0.f) { int p = atomicAdd(&cnt, 1); if (p < CAP) idx[p] = 4 * c4 + 1; }
    if (g.z != 0.f) { int p = atomicAdd(&cnt, 1); if (p < CAP) idx[p] = 4 * c4 + 2; }
    if (g.w != 0.f) { int p = atomicAdd(&cnt, 1); if (p < CAP) idx[p] = 4 * c4 + 3; }
  }
  __syncthreads();
  const int m = min(cnt, CAP);

  // ---- Phase B: scores s_e = dot(h_i, h_j)   (one edge per lane)
  const float4* h4 = (const float4*)hi;
  for (int e = tid; e < m; e += 256) {
    const int j = idx[e];
    const float4* hj = (const float4*)(h + (size_t)j * Dd);
    float s0 = 0.f, s1 = 0.f, s2 = 0.f, s3 = 0.f;
#pragma unroll
    for (int k = 0; k < Dd / 4; ++k) {
      const float4 a = h4[k];
      const float4 b = hj[k];
      s0 += a.x * b.x; s1 += a.y * b.y; s2 += a.z * b.z; s3 += a.w * b.w;
    }
    sc[e] = (s0 + s1) + (s2 + s3);
  }
  __syncthreads();

  // ---- Phase C: block max over unmasked scores (s==0 means masked, as in ref)
  float lmax = -INFINITY;
  for (int e = tid; e < m; e += 256) {
    const float s = sc[e];
    if (s != 0.f) lmax = fmaxf(lmax, s);
  }
#pragma unroll
  for (int off = 32; off > 0; off >>= 1) lmax = fmaxf(lmax, __shfl_down(lmax, off));
  const int lane = tid & 63, wv = tid >> 6;
  if (lane == 0) wred[wv] = lmax;
  __syncthreads();
  const float gmax = fmaxf(fmaxf(wred[0], wred[1]), fmaxf(wred[2], wred[3]));
  __syncthreads();  // wred reused below

  // ---- Phase D: p = exp(s - max), block sum
  float lsum = 0.f;
  for (int e = tid; e < m; e += 256) {
    const float s = sc[e];
    const float p = (s != 0.f) ? __expf(s - gmax) : 0.f;
    sc[e] = p;
    lsum += p;
  }
#pragma unroll
  for (int off = 32; off > 0; off >>= 1) lsum += __shfl_down(lsum, off);
  if (lane == 0) wred[wv] = lsum;
  __syncthreads();
  const float gsum = wred[0] + wred[1] + wred[2] + wred[3];
  const float inv = 1.f / gsum;

  // ---- Phase E: out[i][d] = (sum_e p_e * h[j_e][d]) * inv + bias[d]
  const int d = tid & 127;
  const int half = tid >> 7;
  float acc = 0.f;
#pragma unroll 4
  for (int e = half; e < m; e += 2) {
    acc += sc[e] * h[(size_t)idx[e] * Dd + d];  // coalesced 512B row reads (L2)
  }
  if (half == 1) accs[d] = acc;
  __syncthreads();
  if (half == 0) {
    out[(size_t)i * Dd + d] = (acc + accs[d]) * inv + bias[d];
  }
}

extern "C" void kernel_launch(void* const* d_in, const int* in_sizes, int n_in,
                              void* d_out, int out_size, void* d_ws, size_t ws_size,
                              hipStream_t stream) {
  const float* x     = (const float*)d_in[0];  // [1,8192,256]
  const float* graph = (const float*)d_in[1];  // [8192,8192]
  const float* W     = (const float*)d_in[2];  // [128,256]
  const float* bias  = (const float*)d_in[3];  // [128]
  float* out = (float*)d_out;                  // [1,8192,128]
  float* h = (float*)d_ws;                     // 8192*128 fp32 = 4 MB scratch

  h_kernel<<<Nn / 8, 256, 0, stream>>>(x, W, h);
  gat_kernel<<<Nn, 256, 0, stream>>>(graph, h, bias, out);
}